// Round 7
// baseline (1021.345 us; speedup 1.0000x reference)
//
#include <hip/hip_runtime.h>
#include <cstddef>

// ---------------------------------------------------------------------------
// CNN1D_LSTM1, round 7: single persistent mega-kernel (256 blocks x 256 thr,
// 1 block/CU) + manual device-scope grid barriers between phases.
//   P0 prep     (16 blocks)  conv1 eff-weight pack + b_eff
//   P1 conv1p   (1664 tiles) conv 16->32 k30 MFMA + fused maxpool -> S2b bf16
//   P2 conv2    (832 tiles)  conv 32->64 k10 MFMA -> S3 fp32
//   P3 pool+xc  (128 tiles)  adaptive maxpool + conv(64->4,k3,p1)+leaky -> xcbuf
//   P4 xgw      (80 tiles)   Xg gate precompute, coalesced MFMA-C-layout stores
//   P5 lstm     (8 blocks)   batch-split MFMA 16x16x32 bf16 recurrence
//   P6 head     (1 block)    2->1 linear + sigmoid
// Barrier: monotonic arrive counter + generation, __hip_atomic AGENT scope
// (valid across non-coherent XCD L2s); state zeroed by hipMemsetAsync.
// ---------------------------------------------------------------------------

typedef __attribute__((ext_vector_type(8))) short bf16x8;
typedef __attribute__((ext_vector_type(4))) float f32x4;
typedef unsigned int uint32;

__device__ __forceinline__ unsigned short f2bf(float f) {
    unsigned u = __float_as_uint(f);
    u += 0x7fffu + ((u >> 16) & 1u);   // RNE
    return (unsigned short)(u >> 16);
}
__device__ __forceinline__ float bf2f(unsigned short h) {
    return __uint_as_float(((unsigned)h) << 16);
}
__device__ __forceinline__ float sigm(float x) {
    return __builtin_amdgcn_rcpf(1.0f + __expf(-x));
}
__device__ __forceinline__ float tanh_(float x) {
    return 2.0f * __builtin_amdgcn_rcpf(1.0f + __expf(-2.0f * x)) - 1.0f;
}
__device__ __forceinline__ float leaky(float v) { return v >= 0.0f ? v : 0.01f * v; }

union __align__(16) SharedU {
    struct { unsigned short Wl[19200]; unsigned short U[6336]; } c1;   // 51.1 KB
    struct { unsigned short At[3200];  unsigned short Wl[25600]; } c2; // 57.6 KB
    struct { float bufs[4][2][402]; unsigned short Ps[64][302]; } br;  // 51.5 KB
    struct { float xcs[1920]; } xg;                                    //  7.7 KB
    struct { unsigned short h[2][16][72]; } ls;                        //  4.6 KB
};

#define NB 256

__global__ __launch_bounds__(256) void mega_kernel(
    const float* __restrict__ X,
    const float* __restrict__ w_dw, const float* __restrict__ b_dw,
    const float* __restrict__ w_pw, const float* __restrict__ b_pw,
    const float* __restrict__ w_c2, const float* __restrict__ b_c2,
    const float* __restrict__ w_sc0, const float* __restrict__ b_sc0,
    const float* __restrict__ w_ih0, const float* __restrict__ b_ih0, const float* __restrict__ b_hh0,
    const float* __restrict__ w_hh0, const float* __restrict__ w_l0, const float* __restrict__ b_l0,
    const float* __restrict__ w_sc1, const float* __restrict__ b_sc1,
    const float* __restrict__ w_ih1, const float* __restrict__ b_ih1, const float* __restrict__ b_hh1,
    const float* __restrict__ w_hh1, const float* __restrict__ w_l1, const float* __restrict__ b_l1,
    const float* __restrict__ w_rul, const float* __restrict__ b_rul,
    unsigned short* __restrict__ Wp1, float* __restrict__ b_eff,
    unsigned short* __restrict__ S2b, float* __restrict__ S3,
    float* __restrict__ xcbuf, float* __restrict__ Xg0, float* __restrict__ Xg1,
    float* __restrict__ brbuf, unsigned* bar, float* __restrict__ out) {

    __shared__ SharedU S;
    const int tid = threadIdx.x, bid = blockIdx.x;
    unsigned mygen = 0;

    auto gbar = [&]() {
        __syncthreads();
        if (tid == 0) {
            unsigned target = mygen + 1;
            unsigned arrived = __hip_atomic_fetch_add(&bar[0], 1u, __ATOMIC_ACQ_REL,
                                                      __HIP_MEMORY_SCOPE_AGENT) + 1;
            if (arrived == (unsigned)NB * target) {
                __hip_atomic_store(&bar[1], target, __ATOMIC_RELEASE,
                                   __HIP_MEMORY_SCOPE_AGENT);
            } else {
                while (__hip_atomic_load(&bar[1], __ATOMIC_ACQUIRE,
                                         __HIP_MEMORY_SCOPE_AGENT) < target)
                    __builtin_amdgcn_s_sleep(4);
            }
        }
        mygen += 1;
        __syncthreads();
    };

    const int w = tid >> 6, lane = tid & 63, quad = lane >> 4, l16 = lane & 15;

    // ------------------------------------------------------------ P0: prep
    if (bid < 15) {
        const int kc = bid;
        for (int it = 0; it < 4; ++it) {
            int idx = tid + it * 256;
            int n = idx >> 5, kp = idx & 31;
            int ch = kp & 15, kappa = kc * 2 + (kp >> 4);
            float s = 0.f;
            for (int j = 0; j < 16; ++j)
                s += w_pw[n * 256 + ch * 16 + j] * w_dw[(ch * 16 + j) * 30 + kappa];
            Wp1[(kc * 32 + n) * 32 + kp] = f2bf(s);
        }
    } else if (bid == 15 && tid < 32) {
        float s = b_pw[tid];
        for (int c = 0; c < 256; ++c) s += w_pw[tid * 256 + c] * b_dw[c];
        b_eff[tid] = s;
    }
    gbar();

    // ------------------------------------------------------------ P1: conv1p
    {
        const uint32* src = (const uint32*)Wp1;
        uint32* dst = (uint32*)S.c1.Wl;
        for (int i = tid; i < 7680; i += 256)
            dst[(i >> 4) * 20 + (i & 15)] = src[i];
        const int ki = quad >> 1, ch0 = (quad & 1) * 8;
        for (int tile = bid; tile < 1664; tile += NB) {
            const int tx = tile % 26, b = tile / 26;
            const int l0 = tx * 160;
            unsigned short* Xt = S.c1.U;
            for (int i = tid; i < 3584; i += 256) {
                int ch = i / 224, p = i - ch * 224;
                int l = l0 + p;
                float v = (p < 221 && l < 4096) ? X[((size_t)b * 16 + ch) * 4096 + l] : 0.f;
                Xt[p * 24 + ch] = f2bf(v);
            }
            __syncthreads();
            f32x4 acc[3][2];
#pragma unroll
            for (int mi = 0; mi < 3; ++mi)
#pragma unroll
                for (int nt = 0; nt < 2; ++nt) acc[mi][nt] = (f32x4){0.f, 0.f, 0.f, 0.f};
#pragma unroll
            for (int kc = 0; kc < 15; ++kc) {
                bf16x8 B0 = *(const bf16x8*)(S.c1.Wl + (kc * 32 + l16) * 40 + quad * 8);
                bf16x8 B1 = *(const bf16x8*)(S.c1.Wl + (kc * 32 + 16 + l16) * 40 + quad * 8);
#pragma unroll
                for (int mi = 0; mi < 3; ++mi) {
                    int mrow = (w + mi * 4) * 16 + l16 + 2 * kc + ki;
                    bf16x8 A = *(const bf16x8*)(Xt + mrow * 24 + ch0);
                    acc[mi][0] = __builtin_amdgcn_mfma_f32_16x16x32_bf16(A, B0, acc[mi][0], 0, 0, 0);
                    acc[mi][1] = __builtin_amdgcn_mfma_f32_16x16x32_bf16(A, B1, acc[mi][1], 0, 0, 0);
                }
            }
            __syncthreads();
            unsigned short* Ct = S.c1.U;   // [192][33]
#pragma unroll
            for (int mi = 0; mi < 3; ++mi) {
                int lrow = (w + mi * 4) * 16 + quad * 4;
#pragma unroll
                for (int nt = 0; nt < 2; ++nt) {
                    int o = nt * 16 + l16;
                    float be = b_eff[o];
#pragma unroll
                    for (int r = 0; r < 4; ++r)
                        Ct[(lrow + r) * 33 + o] = f2bf(leaky(acc[mi][nt][r] + be));
                }
            }
            __syncthreads();
            for (int idx = tid; idx < 1024; idx += 256) {    // 32 t x 32 ch
                int ti = idx >> 5, ch = idx & 31;
                int t = tx * 32 + ti;
                if (t < 811) {
                    int pmax = 4067 - 5 * t; if (pmax > 20) pmax = 20;
                    int pbase = 5 * ti;
                    float m = bf2f(Ct[pbase * 33 + ch]);
                    for (int p = 1; p < pmax; ++p) m = fmaxf(m, bf2f(Ct[(pbase + p) * 33 + ch]));
                    S2b[((size_t)b * 32 + ch) * 812 + t] = f2bf(m);
                }
            }
            __syncthreads();
        }
    }
    gbar();

    // ------------------------------------------------------------ P2: conv2
    {
        for (int pair = tid; pair < 2048; pair += 256) {
            int n = pair >> 5, kp = pair & 31;
            const float* srcw = w_c2 + n * 320 + kp * 10;
            unsigned short* dstc = S.c2.Wl + n * 40 + kp;
#pragma unroll
            for (int kc = 0; kc < 10; ++kc) dstc[kc * 2560] = f2bf(srcw[kc]);
        }
        const int ch0 = quad * 8;
        for (int tile = bid; tile < 832; tile += NB) {
            const int lx = tile % 13, b = tile / 13, l0 = lx * 64;
            for (int i = tid; i < 2560; i += 256) {
                int ch = i / 80, p = i - ch * 80;
                int l = l0 + p;
                S.c2.At[p * 40 + ch] = (p < 73 && l < 811)
                    ? S2b[((size_t)b * 32 + ch) * 812 + l] : (unsigned short)0;
            }
            __syncthreads();
            const int mA = w * 16 + l16;
            f32x4 acc[4];
#pragma unroll
            for (int nt = 0; nt < 4; ++nt) acc[nt] = (f32x4){0.f, 0.f, 0.f, 0.f};
#pragma unroll
            for (int kc = 0; kc < 10; ++kc) {
                bf16x8 A = *(const bf16x8*)(S.c2.At + (mA + kc) * 40 + ch0);
#pragma unroll
                for (int nt = 0; nt < 4; ++nt) {
                    bf16x8 Bf = *(const bf16x8*)(S.c2.Wl + (kc * 64 + nt * 16 + l16) * 40 + quad * 8);
                    acc[nt] = __builtin_amdgcn_mfma_f32_16x16x32_bf16(A, Bf, acc[nt], 0, 0, 0);
                }
            }
            const int lbase = l0 + w * 16 + quad * 4;
#pragma unroll
            for (int nt = 0; nt < 4; ++nt) {
                int o = nt * 16 + l16;
                float bc = b_c2[o];
#pragma unroll
                for (int r = 0; r < 4; ++r) {
                    int l = lbase + r;
                    if (l < 802) S3[((size_t)b * 64 + o) * 802 + l] = leaky(acc[nt][r] + bc);
                }
            }
            __syncthreads();
        }
    }
    gbar();

    // ------------------------------------------------------------ P3: pool + xc
    if (bid < 128) {
        const int b = bid >> 1, br = bid & 1;
        const int T = br ? 100 : 300;
        const float* w_sc = br ? w_sc1 : w_sc0;
        const float* b_sc = br ? b_sc1 : b_sc0;
        for (int ci = 0; ci < 16; ++ci) {
            const int c = w * 16 + ci;
            const float* row = S3 + ((size_t)b * 64 + c) * 802;
            if (br == 0) {
                float* A = S.br.bufs[w][0];
                float* B = S.br.bufs[w][1];
                for (int it = 0; it < 7; ++it) {
                    int q = lane + it * 64;
                    if (q < 401) A[q] = fmaxf(row[2 * q], row[2 * q + 1]);
                }
                __syncthreads();
                int len = 401;
#pragma unroll
                for (int sp = 1; sp <= 32; sp <<= 1) {
                    int nl = len - sp;
                    for (int it = 0; it < 7; ++it) {
                        int q = lane + it * 64;
                        if (q < nl) B[q] = fmaxf(A[q], A[q + sp]);
                    }
                    __syncthreads();
                    float* tmp = A; A = B; B = tmp; len = nl;
                }
                for (int it = 0; it < 5; ++it) {
                    int t = lane + it * 64;
                    if (t < 300) S.br.Ps[c][1 + t] = f2bf(fmaxf(A[t], A[t + 38]));
                }
                if (lane < 2) S.br.Ps[c][lane * 301] = 0;
            } else {
                for (int it = 0; it < 2; ++it) {
                    int t = lane + it * 64;
                    if (t < 100) {
                        float m = row[8 * t];
#pragma unroll
                        for (int p = 1; p < 10; ++p) m = fmaxf(m, row[8 * t + p]);
                        S.br.Ps[c][1 + t] = f2bf(m);
                    }
                }
                if (lane < 2) S.br.Ps[c][lane * 101] = 0;
            }
        }
        __syncthreads();
        for (int i = tid; i < 4 * T; i += 256) {
            int o = i / T, t = i - o * T;
            float sum = b_sc[o];
            const float* wvp = w_sc + o * 192;
            for (int c = 0; c < 64; ++c) {
                float p0 = bf2f(S.br.Ps[c][t]), p1 = bf2f(S.br.Ps[c][t + 1]),
                      p2 = bf2f(S.br.Ps[c][t + 2]);
                sum += wvp[c * 3] * p0 + wvp[c * 3 + 1] * p1 + wvp[c * 3 + 2] * p2;
            }
            xcbuf[((size_t)(br * 64 + b) * 4 + o) * 304 + t] = leaky(sum);
        }
    }
    gbar();

    // ------------------------------------------------------------ P4: xgw
    if (bid < 80) {
        const int bt = bid & 3, br = (bid >> 2) & 1, chunk = bid >> 3;
        const int CH = br ? 10 : 30;
        const int t0 = chunk * CH;
        const float* w_ih = br ? w_ih1 : w_ih0;
        const float* b_ih = br ? b_ih1 : b_ih0;
        const float* b_hh = br ? b_hh1 : b_hh0;
        float* Xg = br ? Xg1 : Xg0;
        const int n16 = CH * 16;
        for (int idx = tid; idx < 4 * n16; idx += 256) {
            int bi = idx & 15, tc = (idx >> 4) % CH, kk = idx / n16;
            S.xg.xcs[(kk * CH + tc) * 16 + bi] =
                xcbuf[((size_t)(br * 64 + bt * 16 + bi) * 4 + kk) * 304 + t0 + tc];
        }
        __syncthreads();
        const int q2 = tid >> 6, l2 = (tid >> 2) & 15, g = tid & 3;
        float4 wk[4]; float bk[4];
#pragma unroll
        for (int k = 0; k < 4; ++k) {
            int n = g * 64 + k * 16 + l2;
            wk[k] = *(const float4*)(w_ih + n * 4);
            bk[k] = b_ih[n] + b_hh[n];
        }
        for (int tc = 0; tc < CH; ++tc) {
            f32x4 xv[4];
#pragma unroll
            for (int kk = 0; kk < 4; ++kk)
                xv[kk] = *(const f32x4*)(S.xg.xcs + (kk * CH + tc) * 16 + q2 * 4);
            float* dst = Xg + (size_t)(t0 + tc) * 16384 + bt * 4096 + 4 * tid;
#pragma unroll
            for (int k = 0; k < 4; ++k) {
                f32x4 o4;
#pragma unroll
                for (int j = 0; j < 4; ++j)
                    o4[j] = bk[k] + wk[k].x * xv[0][j] + wk[k].y * xv[1][j]
                                  + wk[k].z * xv[2][j] + wk[k].w * xv[3][j];
                *(f32x4*)(dst + k * 1024) = o4;
            }
        }
    }
    gbar();

    // ------------------------------------------------------------ P5: lstm
    if (bid < 8) {
        const int bt = bid & 3, br = bid >> 2;
        const int T = (br == 0) ? 300 : 100;
        const float* Xg = (br == 0) ? Xg0 : Xg1;
        const float* Whh = (br == 0) ? w_hh0 : w_hh1;
        const float* wl = (br == 0) ? w_l0 : w_l1;
        const float* bl = (br == 0) ? b_l0 : b_l1;
        const int hidx = w * 16 + l16;

        bf16x8 Bf[4][2];
#pragma unroll
        for (int g = 0; g < 4; ++g) {
            const int n = g * 64 + hidx;
#pragma unroll
            for (int kc = 0; kc < 2; ++kc) {
                const float* src = Whh + n * 64 + kc * 32 + quad * 8;
                bf16x8 v;
#pragma unroll
                for (int j = 0; j < 8; ++j) v[j] = (short)f2bf(src[j]);
                Bf[g][kc] = v;
            }
        }
        for (int i = tid; i < 2 * 16 * 72; i += 256) (&S.ls.h[0][0][0])[i] = 0;

        const float* xp = Xg + ((size_t)bt * 4 + w) * 1024 + lane * 16;
        f32x4 xb0[4], xb1[4];
#pragma unroll
        for (int g = 0; g < 4; ++g) xb0[g] = *(const f32x4*)(xp + g * 4);
#pragma unroll
        for (int g = 0; g < 4; ++g) xb1[g] = *(const f32x4*)(xp + 16384 + g * 4);

        float c[4] = {0.f, 0.f, 0.f, 0.f};
        __syncthreads();

        auto step = [&](int t, f32x4* xb) {
            const unsigned short* hrow = &S.ls.h[t & 1][l16][0];
            bf16x8 A0 = *(const bf16x8*)(hrow + quad * 8);
            bf16x8 A1 = *(const bf16x8*)(hrow + 32 + quad * 8);
            f32x4 ac[4];
#pragma unroll
            for (int g = 0; g < 4; ++g) {
                ac[g] = __builtin_amdgcn_mfma_f32_16x16x32_bf16(A0, Bf[g][0], xb[g], 0, 0, 0);
                ac[g] = __builtin_amdgcn_mfma_f32_16x16x32_bf16(A1, Bf[g][1], ac[g], 0, 0, 0);
            }
            if (t + 2 < T) {
                const float* np = xp + (size_t)(t + 2) * 16384;
#pragma unroll
                for (int g = 0; g < 4; ++g) xb[g] = *(const f32x4*)(np + g * 4);
            }
            const int nb = (t + 1) & 1;
#pragma unroll
            for (int r = 0; r < 4; ++r) {
                float iv = sigm(ac[0][r]);
                float fv = sigm(ac[1][r]);
                float gv = tanh_(ac[2][r]);
                float ov = sigm(ac[3][r]);
                float cs = fv * c[r] + iv * gv;
                c[r] = cs;
                S.ls.h[nb][quad * 4 + r][hidx] = f2bf(ov * tanh_(cs));
            }
            __syncthreads();
        };

        for (int t = 0; t < T; t += 2) {   // T even
            step(t, xb0);
            step(t + 1, xb1);
        }

        if (tid < 16) {
            const unsigned short* hrow = &S.ls.h[0][tid][0];
            float s = bl[0];
            for (int j = 0; j < 64; ++j) s += bf2f(hrow[j]) * wl[j];
            brbuf[br * 64 + bt * 16 + tid] = s;
        }
    }
    gbar();

    // ------------------------------------------------------------ P6: head
    if (bid == 0 && tid < 64) {
        float v0 = brbuf[tid], v1 = brbuf[64 + tid];
        float v = w_rul[0] * v0 + w_rul[1] * v1 + b_rul[0];
        out[tid] = sigm(v);
    }
}

// ---------------------------------------------------------------------------
extern "C" void kernel_launch(void* const* d_in, const int* in_sizes, int n_in,
                              void* d_out, int out_size, void* d_ws, size_t ws_size,
                              hipStream_t stream) {
    const float* X     = (const float*)d_in[0];
    const float* w_dw  = (const float*)d_in[1];
    const float* b_dw  = (const float*)d_in[2];
    const float* w_pw  = (const float*)d_in[3];
    const float* b_pw  = (const float*)d_in[4];
    const float* w_c2  = (const float*)d_in[5];
    const float* b_c2  = (const float*)d_in[6];
    const float* w_sc0 = (const float*)d_in[7];
    const float* b_sc0 = (const float*)d_in[8];
    const float* w_ih0 = (const float*)d_in[9];
    const float* b_ih0 = (const float*)d_in[10];
    const float* w_hh0 = (const float*)d_in[11];
    const float* b_hh0 = (const float*)d_in[12];
    const float* w_l0  = (const float*)d_in[13];
    const float* b_l0  = (const float*)d_in[14];
    const float* w_sc1 = (const float*)d_in[15];
    const float* b_sc1 = (const float*)d_in[16];
    const float* w_ih1 = (const float*)d_in[17];
    const float* b_ih1 = (const float*)d_in[18];
    const float* w_hh1 = (const float*)d_in[19];
    const float* b_hh1 = (const float*)d_in[20];
    const float* w_l1  = (const float*)d_in[21];
    const float* b_l1  = (const float*)d_in[22];
    const float* w_rul = (const float*)d_in[23];
    const float* b_rul = (const float*)d_in[24];

    float* ws = (float*)d_ws;
    float* Xg0 = ws;                                           // 4,915,200 f
    float* Xg1 = ws + 4915200;                                 // 1,638,400 f
    unsigned short* S2b = (unsigned short*)(ws + 6553600);     // 1,662,976 sh
    float* S3    = ws + 7385088;                               // 3,284,992 f
    float* xcbuf = ws + 10670080;                              // 155,648 f
    unsigned short* Wp1 = (unsigned short*)(ws + 10825728);    // 15,360 sh
    float* b_eff = ws + 10833408;                              // 32
    float* brbuf = ws + 10833440;                              // 128
    unsigned* bar = (unsigned*)(ws + 10833568);                // 2  (~43.3 MB)

    hipMemsetAsync(bar, 0, 2 * sizeof(unsigned), stream);
    mega_kernel<<<NB, 256, 0, stream>>>(
        X, w_dw, b_dw, w_pw, b_pw, w_c2, b_c2,
        w_sc0, b_sc0, w_ih0, b_ih0, b_hh0, w_hh0, w_l0, b_l0,
        w_sc1, b_sc1, w_ih1, b_ih1, b_hh1, w_hh1, w_l1, b_l1,
        w_rul, b_rul,
        Wp1, b_eff, S2b, S3, xcbuf, Xg0, Xg1, brbuf, bar, (float*)d_out);
}

// Round 8
// 553.030 us; speedup vs baseline: 1.8468x; 1.8468x over previous
//
#include <hip/hip_runtime.h>
#include <cstddef>

// ---------------------------------------------------------------------------
// CNN1D_LSTM1, round 8: single persistent mega-kernel (256 blocks x 256 thr,
// 1 block/CU) + manual device-scope grid barriers between phases.
// ROUND-8 FIX: barrier poll loop uses RELAXED agent loads (sc1, no cache
// invalidation) + ONE acquire load after exit. Round 7 polled with ACQUIRE,
// which emits buffer_inv (L2 invalidate) on EVERY poll from 248 spinning
// blocks -> chip-wide L2 invalidation storm (FETCH 13->42MB, 101 GB/s HBM).
//   P0 prep     (16 blocks)  conv1 eff-weight pack + b_eff
//   P1 conv1p   (1664 tiles) conv 16->32 k30 MFMA + fused maxpool -> S2b bf16
//   P2 conv2    (832 tiles)  conv 32->64 k10 MFMA -> S3 fp32
//   P3 pool+xc  (128 tiles)  adaptive maxpool + conv(64->4,k3,p1)+leaky -> xcbuf
//   P4 xgw      (80 tiles)   Xg gate precompute, coalesced MFMA-C-layout stores
//   P5 lstm     (8 blocks)   batch-split MFMA 16x16x32 bf16 recurrence
//   P6 head     (1 block)    2->1 linear + sigmoid
// ---------------------------------------------------------------------------

typedef __attribute__((ext_vector_type(8))) short bf16x8;
typedef __attribute__((ext_vector_type(4))) float f32x4;
typedef unsigned int uint32;

__device__ __forceinline__ unsigned short f2bf(float f) {
    unsigned u = __float_as_uint(f);
    u += 0x7fffu + ((u >> 16) & 1u);   // RNE
    return (unsigned short)(u >> 16);
}
__device__ __forceinline__ float bf2f(unsigned short h) {
    return __uint_as_float(((unsigned)h) << 16);
}
__device__ __forceinline__ float sigm(float x) {
    return __builtin_amdgcn_rcpf(1.0f + __expf(-x));
}
__device__ __forceinline__ float tanh_(float x) {
    return 2.0f * __builtin_amdgcn_rcpf(1.0f + __expf(-2.0f * x)) - 1.0f;
}
__device__ __forceinline__ float leaky(float v) { return v >= 0.0f ? v : 0.01f * v; }

union __align__(16) SharedU {
    struct { unsigned short Wl[19200]; unsigned short U[6336]; } c1;   // 51.1 KB
    struct { unsigned short At[3200];  unsigned short Wl[25600]; } c2; // 57.6 KB
    struct { float bufs[4][2][402]; unsigned short Ps[64][302]; } br;  // 51.5 KB
    struct { float xcs[1920]; } xg;                                    //  7.7 KB
    struct { unsigned short h[2][16][72]; } ls;                        //  4.6 KB
};

#define NB 256

__global__ __launch_bounds__(256) void mega_kernel(
    const float* __restrict__ X,
    const float* __restrict__ w_dw, const float* __restrict__ b_dw,
    const float* __restrict__ w_pw, const float* __restrict__ b_pw,
    const float* __restrict__ w_c2, const float* __restrict__ b_c2,
    const float* __restrict__ w_sc0, const float* __restrict__ b_sc0,
    const float* __restrict__ w_ih0, const float* __restrict__ b_ih0, const float* __restrict__ b_hh0,
    const float* __restrict__ w_hh0, const float* __restrict__ w_l0, const float* __restrict__ b_l0,
    const float* __restrict__ w_sc1, const float* __restrict__ b_sc1,
    const float* __restrict__ w_ih1, const float* __restrict__ b_ih1, const float* __restrict__ b_hh1,
    const float* __restrict__ w_hh1, const float* __restrict__ w_l1, const float* __restrict__ b_l1,
    const float* __restrict__ w_rul, const float* __restrict__ b_rul,
    unsigned short* __restrict__ Wp1, float* __restrict__ b_eff,
    unsigned short* __restrict__ S2b, float* __restrict__ S3,
    float* __restrict__ xcbuf, float* __restrict__ Xg0, float* __restrict__ Xg1,
    float* __restrict__ brbuf, unsigned* bar, float* __restrict__ out) {

    __shared__ SharedU S;
    const int tid = threadIdx.x, bid = blockIdx.x;
    unsigned mygen = 0;

    auto gbar = [&]() {
        __syncthreads();
        if (tid == 0) {
            unsigned target = mygen + 1;
            unsigned arrived = __hip_atomic_fetch_add(&bar[0], 1u, __ATOMIC_ACQ_REL,
                                                      __HIP_MEMORY_SCOPE_AGENT) + 1;
            if (arrived == (unsigned)NB * target) {
                __hip_atomic_store(&bar[1], target, __ATOMIC_RELEASE,
                                   __HIP_MEMORY_SCOPE_AGENT);
            } else {
                // RELAXED poll: sc1 load from memory-side, NO cache invalidate
                while (__hip_atomic_load(&bar[1], __ATOMIC_RELAXED,
                                         __HIP_MEMORY_SCOPE_AGENT) < target)
                    __builtin_amdgcn_s_sleep(8);
                // single acquire for data visibility (one buffer_inv, not per-poll)
                (void)__hip_atomic_load(&bar[1], __ATOMIC_ACQUIRE,
                                        __HIP_MEMORY_SCOPE_AGENT);
            }
        }
        mygen += 1;
        __syncthreads();
    };

    const int w = tid >> 6, lane = tid & 63, quad = lane >> 4, l16 = lane & 15;

    // ------------------------------------------------------------ P0: prep
    if (bid < 15) {
        const int kc = bid;
        for (int it = 0; it < 4; ++it) {
            int idx = tid + it * 256;
            int n = idx >> 5, kp = idx & 31;
            int ch = kp & 15, kappa = kc * 2 + (kp >> 4);
            float s = 0.f;
            for (int j = 0; j < 16; ++j)
                s += w_pw[n * 256 + ch * 16 + j] * w_dw[(ch * 16 + j) * 30 + kappa];
            Wp1[(kc * 32 + n) * 32 + kp] = f2bf(s);
        }
    } else if (bid == 15 && tid < 32) {
        float s = b_pw[tid];
        for (int c = 0; c < 256; ++c) s += w_pw[tid * 256 + c] * b_dw[c];
        b_eff[tid] = s;
    }
    gbar();

    // ------------------------------------------------------------ P1: conv1p
    {
        const uint32* src = (const uint32*)Wp1;
        uint32* dst = (uint32*)S.c1.Wl;
        for (int i = tid; i < 7680; i += 256)
            dst[(i >> 4) * 20 + (i & 15)] = src[i];
        const int ki = quad >> 1, ch0 = (quad & 1) * 8;
        for (int tile = bid; tile < 1664; tile += NB) {
            const int tx = tile % 26, b = tile / 26;
            const int l0 = tx * 160;
            unsigned short* Xt = S.c1.U;
            for (int i = tid; i < 3584; i += 256) {
                int ch = i / 224, p = i - ch * 224;
                int l = l0 + p;
                float v = (p < 221 && l < 4096) ? X[((size_t)b * 16 + ch) * 4096 + l] : 0.f;
                Xt[p * 24 + ch] = f2bf(v);
            }
            __syncthreads();
            f32x4 acc[3][2];
#pragma unroll
            for (int mi = 0; mi < 3; ++mi)
#pragma unroll
                for (int nt = 0; nt < 2; ++nt) acc[mi][nt] = (f32x4){0.f, 0.f, 0.f, 0.f};
#pragma unroll
            for (int kc = 0; kc < 15; ++kc) {
                bf16x8 B0 = *(const bf16x8*)(S.c1.Wl + (kc * 32 + l16) * 40 + quad * 8);
                bf16x8 B1 = *(const bf16x8*)(S.c1.Wl + (kc * 32 + 16 + l16) * 40 + quad * 8);
#pragma unroll
                for (int mi = 0; mi < 3; ++mi) {
                    int mrow = (w + mi * 4) * 16 + l16 + 2 * kc + ki;
                    bf16x8 A = *(const bf16x8*)(Xt + mrow * 24 + ch0);
                    acc[mi][0] = __builtin_amdgcn_mfma_f32_16x16x32_bf16(A, B0, acc[mi][0], 0, 0, 0);
                    acc[mi][1] = __builtin_amdgcn_mfma_f32_16x16x32_bf16(A, B1, acc[mi][1], 0, 0, 0);
                }
            }
            __syncthreads();
            unsigned short* Ct = S.c1.U;   // [192][33]
#pragma unroll
            for (int mi = 0; mi < 3; ++mi) {
                int lrow = (w + mi * 4) * 16 + quad * 4;
#pragma unroll
                for (int nt = 0; nt < 2; ++nt) {
                    int o = nt * 16 + l16;
                    float be = b_eff[o];
#pragma unroll
                    for (int r = 0; r < 4; ++r)
                        Ct[(lrow + r) * 33 + o] = f2bf(leaky(acc[mi][nt][r] + be));
                }
            }
            __syncthreads();
            for (int idx = tid; idx < 1024; idx += 256) {    // 32 t x 32 ch
                int ti = idx >> 5, ch = idx & 31;
                int t = tx * 32 + ti;
                if (t < 811) {
                    int pmax = 4067 - 5 * t; if (pmax > 20) pmax = 20;
                    int pbase = 5 * ti;
                    float m = bf2f(Ct[pbase * 33 + ch]);
                    for (int p = 1; p < pmax; ++p) m = fmaxf(m, bf2f(Ct[(pbase + p) * 33 + ch]));
                    S2b[((size_t)b * 32 + ch) * 812 + t] = f2bf(m);
                }
            }
            __syncthreads();
        }
    }
    gbar();

    // ------------------------------------------------------------ P2: conv2
    {
        for (int pair = tid; pair < 2048; pair += 256) {
            int n = pair >> 5, kp = pair & 31;
            const float* srcw = w_c2 + n * 320 + kp * 10;
            unsigned short* dstc = S.c2.Wl + n * 40 + kp;
#pragma unroll
            for (int kc = 0; kc < 10; ++kc) dstc[kc * 2560] = f2bf(srcw[kc]);
        }
        const int ch0 = quad * 8;
        for (int tile = bid; tile < 832; tile += NB) {
            const int lx = tile % 13, b = tile / 13, l0 = lx * 64;
            for (int i = tid; i < 2560; i += 256) {
                int ch = i / 80, p = i - ch * 80;
                int l = l0 + p;
                S.c2.At[p * 40 + ch] = (p < 73 && l < 811)
                    ? S2b[((size_t)b * 32 + ch) * 812 + l] : (unsigned short)0;
            }
            __syncthreads();
            const int mA = w * 16 + l16;
            f32x4 acc[4];
#pragma unroll
            for (int nt = 0; nt < 4; ++nt) acc[nt] = (f32x4){0.f, 0.f, 0.f, 0.f};
#pragma unroll
            for (int kc = 0; kc < 10; ++kc) {
                bf16x8 A = *(const bf16x8*)(S.c2.At + (mA + kc) * 40 + ch0);
#pragma unroll
                for (int nt = 0; nt < 4; ++nt) {
                    bf16x8 Bf = *(const bf16x8*)(S.c2.Wl + (kc * 64 + nt * 16 + l16) * 40 + quad * 8);
                    acc[nt] = __builtin_amdgcn_mfma_f32_16x16x32_bf16(A, Bf, acc[nt], 0, 0, 0);
                }
            }
            const int lbase = l0 + w * 16 + quad * 4;
#pragma unroll
            for (int nt = 0; nt < 4; ++nt) {
                int o = nt * 16 + l16;
                float bc = b_c2[o];
#pragma unroll
                for (int r = 0; r < 4; ++r) {
                    int l = lbase + r;
                    if (l < 802) S3[((size_t)b * 64 + o) * 802 + l] = leaky(acc[nt][r] + bc);
                }
            }
            __syncthreads();
        }
    }
    gbar();

    // ------------------------------------------------------------ P3: pool + xc
    if (bid < 128) {
        const int b = bid >> 1, br = bid & 1;
        const int T = br ? 100 : 300;
        const float* w_sc = br ? w_sc1 : w_sc0;
        const float* b_sc = br ? b_sc1 : b_sc0;
        for (int ci = 0; ci < 16; ++ci) {
            const int c = w * 16 + ci;
            const float* row = S3 + ((size_t)b * 64 + c) * 802;
            if (br == 0) {
                float* A = S.br.bufs[w][0];
                float* B = S.br.bufs[w][1];
                for (int it = 0; it < 7; ++it) {
                    int q = lane + it * 64;
                    if (q < 401) A[q] = fmaxf(row[2 * q], row[2 * q + 1]);
                }
                __syncthreads();
                int len = 401;
#pragma unroll
                for (int sp = 1; sp <= 32; sp <<= 1) {
                    int nl = len - sp;
                    for (int it = 0; it < 7; ++it) {
                        int q = lane + it * 64;
                        if (q < nl) B[q] = fmaxf(A[q], A[q + sp]);
                    }
                    __syncthreads();
                    float* tmp = A; A = B; B = tmp; len = nl;
                }
                for (int it = 0; it < 5; ++it) {
                    int t = lane + it * 64;
                    if (t < 300) S.br.Ps[c][1 + t] = f2bf(fmaxf(A[t], A[t + 38]));
                }
                if (lane < 2) S.br.Ps[c][lane * 301] = 0;
            } else {
                for (int it = 0; it < 2; ++it) {
                    int t = lane + it * 64;
                    if (t < 100) {
                        float m = row[8 * t];
#pragma unroll
                        for (int p = 1; p < 10; ++p) m = fmaxf(m, row[8 * t + p]);
                        S.br.Ps[c][1 + t] = f2bf(m);
                    }
                }
                if (lane < 2) S.br.Ps[c][lane * 101] = 0;
            }
        }
        __syncthreads();
        for (int i = tid; i < 4 * T; i += 256) {
            int o = i / T, t = i - o * T;
            float sum = b_sc[o];
            const float* wvp = w_sc + o * 192;
            for (int c = 0; c < 64; ++c) {
                float p0 = bf2f(S.br.Ps[c][t]), p1 = bf2f(S.br.Ps[c][t + 1]),
                      p2 = bf2f(S.br.Ps[c][t + 2]);
                sum += wvp[c * 3] * p0 + wvp[c * 3 + 1] * p1 + wvp[c * 3 + 2] * p2;
            }
            xcbuf[((size_t)(br * 64 + b) * 4 + o) * 304 + t] = leaky(sum);
        }
    }
    gbar();

    // ------------------------------------------------------------ P4: xgw
    if (bid < 80) {
        const int bt = bid & 3, br = (bid >> 2) & 1, chunk = bid >> 3;
        const int CH = br ? 10 : 30;
        const int t0 = chunk * CH;
        const float* w_ih = br ? w_ih1 : w_ih0;
        const float* b_ih = br ? b_ih1 : b_ih0;
        const float* b_hh = br ? b_hh1 : b_hh0;
        float* Xg = br ? Xg1 : Xg0;
        const int n16 = CH * 16;
        for (int idx = tid; idx < 4 * n16; idx += 256) {
            int bi = idx & 15, tc = (idx >> 4) % CH, kk = idx / n16;
            S.xg.xcs[(kk * CH + tc) * 16 + bi] =
                xcbuf[((size_t)(br * 64 + bt * 16 + bi) * 4 + kk) * 304 + t0 + tc];
        }
        __syncthreads();
        const int q2 = tid >> 6, l2 = (tid >> 2) & 15, g = tid & 3;
        float4 wk[4]; float bk[4];
#pragma unroll
        for (int k = 0; k < 4; ++k) {
            int n = g * 64 + k * 16 + l2;
            wk[k] = *(const float4*)(w_ih + n * 4);
            bk[k] = b_ih[n] + b_hh[n];
        }
        for (int tc = 0; tc < CH; ++tc) {
            f32x4 xv[4];
#pragma unroll
            for (int kk = 0; kk < 4; ++kk)
                xv[kk] = *(const f32x4*)(S.xg.xcs + (kk * CH + tc) * 16 + q2 * 4);
            float* dst = Xg + (size_t)(t0 + tc) * 16384 + bt * 4096 + 4 * tid;
#pragma unroll
            for (int k = 0; k < 4; ++k) {
                f32x4 o4;
#pragma unroll
                for (int j = 0; j < 4; ++j)
                    o4[j] = bk[k] + wk[k].x * xv[0][j] + wk[k].y * xv[1][j]
                                  + wk[k].z * xv[2][j] + wk[k].w * xv[3][j];
                *(f32x4*)(dst + k * 1024) = o4;
            }
        }
    }
    gbar();

    // ------------------------------------------------------------ P5: lstm
    if (bid < 8) {
        const int bt = bid & 3, br = bid >> 2;
        const int T = (br == 0) ? 300 : 100;
        const float* Xg = (br == 0) ? Xg0 : Xg1;
        const float* Whh = (br == 0) ? w_hh0 : w_hh1;
        const float* wl = (br == 0) ? w_l0 : w_l1;
        const float* bl = (br == 0) ? b_l0 : b_l1;
        const int hidx = w * 16 + l16;

        bf16x8 Bf[4][2];
#pragma unroll
        for (int g = 0; g < 4; ++g) {
            const int n = g * 64 + hidx;
#pragma unroll
            for (int kc = 0; kc < 2; ++kc) {
                const float* src = Whh + n * 64 + kc * 32 + quad * 8;
                bf16x8 v;
#pragma unroll
                for (int j = 0; j < 8; ++j) v[j] = (short)f2bf(src[j]);
                Bf[g][kc] = v;
            }
        }
        for (int i = tid; i < 2 * 16 * 72; i += 256) (&S.ls.h[0][0][0])[i] = 0;

        const float* xp = Xg + ((size_t)bt * 4 + w) * 1024 + lane * 16;
        f32x4 xb0[4], xb1[4];
#pragma unroll
        for (int g = 0; g < 4; ++g) xb0[g] = *(const f32x4*)(xp + g * 4);
#pragma unroll
        for (int g = 0; g < 4; ++g) xb1[g] = *(const f32x4*)(xp + 16384 + g * 4);

        float c[4] = {0.f, 0.f, 0.f, 0.f};
        __syncthreads();

        auto step = [&](int t, f32x4* xb) {
            const unsigned short* hrow = &S.ls.h[t & 1][l16][0];
            bf16x8 A0 = *(const bf16x8*)(hrow + quad * 8);
            bf16x8 A1 = *(const bf16x8*)(hrow + 32 + quad * 8);
            f32x4 ac[4];
#pragma unroll
            for (int g = 0; g < 4; ++g) {
                ac[g] = __builtin_amdgcn_mfma_f32_16x16x32_bf16(A0, Bf[g][0], xb[g], 0, 0, 0);
                ac[g] = __builtin_amdgcn_mfma_f32_16x16x32_bf16(A1, Bf[g][1], ac[g], 0, 0, 0);
            }
            if (t + 2 < T) {
                const float* np = xp + (size_t)(t + 2) * 16384;
#pragma unroll
                for (int g = 0; g < 4; ++g) xb[g] = *(const f32x4*)(np + g * 4);
            }
            const int nb = (t + 1) & 1;
#pragma unroll
            for (int r = 0; r < 4; ++r) {
                float iv = sigm(ac[0][r]);
                float fv = sigm(ac[1][r]);
                float gv = tanh_(ac[2][r]);
                float ov = sigm(ac[3][r]);
                float cs = fv * c[r] + iv * gv;
                c[r] = cs;
                S.ls.h[nb][quad * 4 + r][hidx] = f2bf(ov * tanh_(cs));
            }
            __syncthreads();
        };

        for (int t = 0; t < T; t += 2) {   // T even
            step(t, xb0);
            step(t + 1, xb1);
        }

        if (tid < 16) {
            const unsigned short* hrow = &S.ls.h[0][tid][0];
            float s = bl[0];
            for (int j = 0; j < 64; ++j) s += bf2f(hrow[j]) * wl[j];
            brbuf[br * 64 + bt * 16 + tid] = s;
        }
    }
    gbar();

    // ------------------------------------------------------------ P6: head
    if (bid == 0 && tid < 64) {
        float v0 = brbuf[tid], v1 = brbuf[64 + tid];
        float v = w_rul[0] * v0 + w_rul[1] * v1 + b_rul[0];
        out[tid] = sigm(v);
    }
}

// ---------------------------------------------------------------------------
extern "C" void kernel_launch(void* const* d_in, const int* in_sizes, int n_in,
                              void* d_out, int out_size, void* d_ws, size_t ws_size,
                              hipStream_t stream) {
    const float* X     = (const float*)d_in[0];
    const float* w_dw  = (const float*)d_in[1];
    const float* b_dw  = (const float*)d_in[2];
    const float* w_pw  = (const float*)d_in[3];
    const float* b_pw  = (const float*)d_in[4];
    const float* w_c2  = (const float*)d_in[5];
    const float* b_c2  = (const float*)d_in[6];
    const float* w_sc0 = (const float*)d_in[7];
    const float* b_sc0 = (const float*)d_in[8];
    const float* w_ih0 = (const float*)d_in[9];
    const float* b_ih0 = (const float*)d_in[10];
    const float* w_hh0 = (const float*)d_in[11];
    const float* b_hh0 = (const float*)d_in[12];
    const float* w_l0  = (const float*)d_in[13];
    const float* b_l0  = (const float*)d_in[14];
    const float* w_sc1 = (const float*)d_in[15];
    const float* b_sc1 = (const float*)d_in[16];
    const float* w_ih1 = (const float*)d_in[17];
    const float* b_ih1 = (const float*)d_in[18];
    const float* w_hh1 = (const float*)d_in[19];
    const float* b_hh1 = (const float*)d_in[20];
    const float* w_l1  = (const float*)d_in[21];
    const float* b_l1  = (const float*)d_in[22];
    const float* w_rul = (const float*)d_in[23];
    const float* b_rul = (const float*)d_in[24];

    float* ws = (float*)d_ws;
    float* Xg0 = ws;                                           // 4,915,200 f
    float* Xg1 = ws + 4915200;                                 // 1,638,400 f
    unsigned short* S2b = (unsigned short*)(ws + 6553600);     // 1,662,976 sh
    float* S3    = ws + 7385088;                               // 3,284,992 f
    float* xcbuf = ws + 10670080;                              // 155,648 f
    unsigned short* Wp1 = (unsigned short*)(ws + 10825728);    // 15,360 sh
    float* b_eff = ws + 10833408;                              // 32
    float* brbuf = ws + 10833440;                              // 128
    unsigned* bar = (unsigned*)(ws + 10833568);                // 2  (~43.3 MB)

    hipMemsetAsync(bar, 0, 2 * sizeof(unsigned), stream);
    mega_kernel<<<NB, 256, 0, stream>>>(
        X, w_dw, b_dw, w_pw, b_pw, w_c2, b_c2,
        w_sc0, b_sc0, w_ih0, b_ih0, b_hh0, w_hh0, w_l0, b_l0,
        w_sc1, b_sc1, w_ih1, b_ih1, b_hh1, w_hh1, w_l1, b_l1,
        w_rul, b_rul,
        Wp1, b_eff, S2b, S3, xcbuf, Xg0, Xg1, brbuf, bar, (float*)d_out);
}

// Round 9
// 421.385 us; speedup vs baseline: 2.4238x; 1.3124x over previous
//
#include <hip/hip_runtime.h>
#include <cstddef>

// ---------------------------------------------------------------------------
// CNN1D_LSTM1 pipeline, round 9: r6 5-launch structure (best known: 444us)
//   prep:   conv1 effective-weight pack (bf16 B-fragments) + b_eff
//   conv1p: conv 16->32 k30 MFMA + fused maxpool(k20,s5,ceil) -> S2b bf16
//           (float4 X staging, dwordx4 weight staging; resets lstm counter)
//   conv2:  conv 32->64 k10 MFMA (self-packs weights) -> S3 fp32
//   branch: adaptive maxpool + conv(64->4,k3,p1)+leaky + Xg store
//           (NO intra-pool barriers: per-wave-private doubling buffers;
//            Xg pre-scaled by -log2e / -2log2e so lstm uses raw exp2)
//   lstm:   batch-split MFMA 16x16x32 bf16, 1 wave/SIMD, exp2 activations,
//           fused head via last-block device-scope atomics
// ---------------------------------------------------------------------------

typedef __attribute__((ext_vector_type(8))) short bf16x8;
typedef __attribute__((ext_vector_type(4))) float f32x4;
typedef unsigned int uint32;

#define LOG2E 1.4426950408889634f

__device__ __forceinline__ unsigned short f2bf(float f) {
    unsigned u = __float_as_uint(f);
    u += 0x7fffu + ((u >> 16) & 1u);   // RNE
    return (unsigned short)(u >> 16);
}
__device__ __forceinline__ float bf2f(unsigned short h) {
    return __uint_as_float(((unsigned)h) << 16);
}
__device__ __forceinline__ float exp2_(float x) {
#if __has_builtin(__builtin_amdgcn_exp2f)
    return __builtin_amdgcn_exp2f(x);
#else
    return __expf(0.6931471805599453f * x);
#endif
}
// rcp2(x) = 1/(1+2^x).  With x pre-scaled by -log2e: == sigmoid(a).
__device__ __forceinline__ float rcp2(float x) {
    return __builtin_amdgcn_rcpf(1.0f + exp2_(x));
}
__device__ __forceinline__ float sigm(float x) {
    return __builtin_amdgcn_rcpf(1.0f + __expf(-x));
}
__device__ __forceinline__ float leaky(float v) { return v >= 0.0f ? v : 0.01f * v; }

// ---------------------------------------------------------------------------
// prep: Wp1[(kc*32+n)*32 + k'] = w_eff(ch=k'&15, kappa=2kc+(k'>>4), o=n); b_eff
__global__ void prep_kernel(const float* __restrict__ w_dw, const float* __restrict__ b_dw,
                            const float* __restrict__ w_pw, const float* __restrict__ b_pw,
                            unsigned short* __restrict__ Wp1, float* __restrict__ b_eff) {
    const int bid = blockIdx.x, tid = threadIdx.x;
    if (bid < 15) {
        const int kc = bid;
        for (int it = 0; it < 4; ++it) {
            int idx = tid + it * 256;
            int n = idx >> 5, kp = idx & 31;
            int ch = kp & 15, kappa = kc * 2 + (kp >> 4);
            float s = 0.f;
            for (int j = 0; j < 16; ++j)
                s += w_pw[n * 256 + ch * 16 + j] * w_dw[(ch * 16 + j) * 30 + kappa];
            Wp1[(kc * 32 + n) * 32 + kp] = f2bf(s);
        }
    } else if (tid < 32) {
        float s = b_pw[tid];
        for (int c = 0; c < 256; ++c) s += w_pw[tid * 256 + c] * b_dw[c];
        b_eff[tid] = s;
    }
}

// ---------------------------------------------------------------------------
// conv1p: grid (26 ttiles, 64 b), 256 thr.  Tile = 32 pool outputs.
__global__ __launch_bounds__(256) void conv1p_kernel(const float* __restrict__ X,
        const unsigned short* __restrict__ Wp1, const float* __restrict__ b_eff,
        unsigned short* __restrict__ S2b, int* __restrict__ cnt) {
    const int b = blockIdx.y, tx = blockIdx.x, tid = threadIdx.x;
    if (tx == 0 && b == 0 && tid == 0) *cnt = 0;   // reset lstm completion counter
    const int l0 = tx * 160;
    __shared__ __align__(16) unsigned short Wl[480 * 40];  // B-frags, rows padded
    __shared__ __align__(16) unsigned short U[192 * 33];   // Xt[224*24] then Ct[192*33]
    unsigned short* Xt = U;
    {   // stage weights: 1920 int4 (rows 16 dw -> padded 20, 16B-aligned)
        const int4* s4 = (const int4*)Wp1;
        for (int j = tid; j < 1920; j += 256)
            *(int4*)((uint32*)Wl + (j >> 2) * 20 + (j & 3) * 4) = s4[j];
    }
    // stage X transposed bf16, float4 global loads
    for (int i = tid; i < 896; i += 256) {
        int ch = i / 56, p4 = (i - ch * 56) * 4;
        int l = l0 + p4;
        float4 v = {0.f, 0.f, 0.f, 0.f};
        const float* xrow = X + ((size_t)b * 16 + ch) * 4096;
        if (l + 3 < 4096 && p4 + 3 < 221) {
            v = *(const float4*)(xrow + l);
        } else {
            float* vv = (float*)&v;
#pragma unroll
            for (int e = 0; e < 4; ++e) {
                int p = p4 + e, le = l + e;
                vv[e] = (p < 221 && le < 4096) ? xrow[le] : 0.f;
            }
        }
        unsigned short* dst = Xt + p4 * 24 + ch;
        dst[0] = f2bf(v.x); dst[24] = f2bf(v.y); dst[48] = f2bf(v.z); dst[72] = f2bf(v.w);
    }
    __syncthreads();
    const int w = tid >> 6, lane = tid & 63, quad = lane >> 4, l16 = lane & 15;
    const int ki = quad >> 1, ch0 = (quad & 1) * 8;
    f32x4 acc[3][2];
#pragma unroll
    for (int mi = 0; mi < 3; ++mi)
#pragma unroll
        for (int nt = 0; nt < 2; ++nt) acc[mi][nt] = (f32x4){0.f, 0.f, 0.f, 0.f};
#pragma unroll
    for (int kc = 0; kc < 15; ++kc) {
        bf16x8 B0 = *(const bf16x8*)(Wl + (kc * 32 + l16) * 40 + quad * 8);
        bf16x8 B1 = *(const bf16x8*)(Wl + (kc * 32 + 16 + l16) * 40 + quad * 8);
#pragma unroll
        for (int mi = 0; mi < 3; ++mi) {
            int mrow = (w + mi * 4) * 16 + l16 + 2 * kc + ki;
            bf16x8 A = *(const bf16x8*)(Xt + mrow * 24 + ch0);
            acc[mi][0] = __builtin_amdgcn_mfma_f32_16x16x32_bf16(A, B0, acc[mi][0], 0, 0, 0);
            acc[mi][1] = __builtin_amdgcn_mfma_f32_16x16x32_bf16(A, B1, acc[mi][1], 0, 0, 0);
        }
    }
    __syncthreads();                 // all Xt reads done; reuse U as Ct
    unsigned short* Ct = U;          // [192][33]
#pragma unroll
    for (int mi = 0; mi < 3; ++mi) {
        int lrow = (w + mi * 4) * 16 + quad * 4;
#pragma unroll
        for (int nt = 0; nt < 2; ++nt) {
            int o = nt * 16 + l16;
            float be = b_eff[o];
#pragma unroll
            for (int r = 0; r < 4; ++r)
                Ct[(lrow + r) * 33 + o] = f2bf(leaky(acc[mi][nt][r] + be));
        }
    }
    __syncthreads();
    for (int idx = tid; idx < 1024; idx += 256) {    // 32 t x 32 ch
        int ti = idx >> 5, ch = idx & 31;
        int t = tx * 32 + ti;
        if (t < 811) {
            int pmax = 4067 - 5 * t; if (pmax > 20) pmax = 20;   // ceil_mode clamp
            int pbase = 5 * ti;
            float m = bf2f(Ct[pbase * 33 + ch]);
            for (int p = 1; p < pmax; ++p) m = fmaxf(m, bf2f(Ct[(pbase + p) * 33 + ch]));
            S2b[((size_t)b * 32 + ch) * 812 + t] = f2bf(m);
        }
    }
}

// ---------------------------------------------------------------------------
// conv2: grid (13 ltiles, 64 b).  M=64, N=64, K=320; self-packs weights.
__global__ __launch_bounds__(256) void conv2_kernel(const unsigned short* __restrict__ S2b,
        const float* __restrict__ w_c2, const float* __restrict__ b_c2,
        float* __restrict__ S3) {
    const int b = blockIdx.y, l0 = blockIdx.x * 64, tid = threadIdx.x;
    __shared__ __align__(16) unsigned short At[80 * 40];
    __shared__ __align__(16) unsigned short Wl[10 * 64 * 40];
    for (int pair = tid; pair < 2048; pair += 256) {   // (n, kp=ch) pairs
        int n = pair >> 5, kp = pair & 31;
        const float* src = w_c2 + n * 320 + kp * 10;
        unsigned short* dstc = Wl + n * 40 + kp;
#pragma unroll
        for (int kc = 0; kc < 10; ++kc) dstc[kc * 2560] = f2bf(src[kc]);
    }
    for (int i = tid; i < 2560; i += 256) {
        int ch = i / 80, p = i - ch * 80;
        int l = l0 + p;
        At[p * 40 + ch] = (p < 73 && l < 811)
            ? S2b[((size_t)b * 32 + ch) * 812 + l] : (unsigned short)0;
    }
    __syncthreads();
    const int w = tid >> 6, lane = tid & 63, quad = lane >> 4, l16 = lane & 15;
    const int mA = w * 16 + l16, ch0 = quad * 8;
    f32x4 acc[4];
#pragma unroll
    for (int nt = 0; nt < 4; ++nt) acc[nt] = (f32x4){0.f, 0.f, 0.f, 0.f};
#pragma unroll
    for (int kc = 0; kc < 10; ++kc) {
        bf16x8 A = *(const bf16x8*)(At + (mA + kc) * 40 + ch0);
#pragma unroll
        for (int nt = 0; nt < 4; ++nt) {
            bf16x8 Bf = *(const bf16x8*)(Wl + (kc * 64 + nt * 16 + l16) * 40 + quad * 8);
            acc[nt] = __builtin_amdgcn_mfma_f32_16x16x32_bf16(A, Bf, acc[nt], 0, 0, 0);
        }
    }
    const int lbase = l0 + w * 16 + quad * 4;
#pragma unroll
    for (int nt = 0; nt < 4; ++nt) {
        int o = nt * 16 + l16;
        float bc = b_c2[o];
#pragma unroll
        for (int r = 0; r < 4; ++r) {
            int l = lbase + r;
            if (l < 802) S3[((size_t)b * 64 + o) * 802 + l] = leaky(acc[nt][r] + bc);
        }
    }
}

// ---------------------------------------------------------------------------
// branch: adaptive maxpool + conv(64->4,k3,p1)+leaky + Xg precompute+store.
// grid (64 b, 2 br), 1024 thr (16 waves x 4 channels, NO intra-pool barriers:
// each wave's doubling buffers are private; same-wave LDS RAW ordered by
// compiler lgkmcnt).  Xg pre-scaled by SCG[g] (-log2e; -2log2e for gate g)
// so the lstm activation is a raw rcp(1+exp2(x)).
__global__ __launch_bounds__(1024) void branch_kernel(const float* __restrict__ S3,
        const float* __restrict__ w_sc0, const float* __restrict__ b_sc0,
        const float* __restrict__ w_ih0, const float* __restrict__ b_ih0, const float* __restrict__ b_hh0,
        const float* __restrict__ w_sc1, const float* __restrict__ b_sc1,
        const float* __restrict__ w_ih1, const float* __restrict__ b_ih1, const float* __restrict__ b_hh1,
        float* __restrict__ Xg0, float* __restrict__ Xg1) {
    const int b = blockIdx.x, br = blockIdx.y;
    const int T = br ? 100 : 300;
    const float* w_sc = br ? w_sc1 : w_sc0;
    const float* b_sc = br ? b_sc1 : b_sc0;
    const float* w_ih = br ? w_ih1 : w_ih0;
    const float* b_ih = br ? b_ih1 : b_ih0;
    const float* b_hh = br ? b_hh1 : b_hh0;
    float* Xg = br ? Xg1 : Xg0;

    __shared__ float bufs[16][2][402];
    __shared__ unsigned short Ps[64][302];   // pooled rows, halo-padded
    __shared__ float xcs[4][304];
    const int tid = threadIdx.x, wv = tid >> 6, lane = tid & 63;

    for (int ci = 0; ci < 4; ++ci) {
        const int c = wv * 4 + ci;
        const float* row = S3 + ((size_t)b * 64 + c) * 802;
        if (br == 0) {
            // bin=300: s=2, k=204 == max over 102 pair-maxes
            float* A = bufs[wv][0];
            float* B = bufs[wv][1];
            for (int it = 0; it < 7; ++it) {
                int q = lane + it * 64;
                if (q < 401) A[q] = fmaxf(row[2 * q], row[2 * q + 1]);
            }
            int len = 401;
#pragma unroll
            for (int sp = 1; sp <= 32; sp <<= 1) {     // doubling -> max of 64
                int nl = len - sp;
                for (int it = 0; it < 7; ++it) {
                    int q = lane + it * 64;
                    if (q < nl) B[q] = fmaxf(A[q], A[q + sp]);
                }
                float* tmp = A; A = B; B = tmp; len = nl;
            }
            for (int it = 0; it < 5; ++it) {           // 102 = [t,t+64)U[t+38,t+102)
                int t = lane + it * 64;
                if (t < 300) Ps[c][1 + t] = f2bf(fmaxf(A[t], A[t + 38]));
            }
            if (lane < 2) Ps[c][lane * 301] = 0;
        } else {
            // bin=100: s=8, k=10 direct
            for (int it = 0; it < 2; ++it) {
                int t = lane + it * 64;
                if (t < 100) {
                    float m = row[8 * t];
#pragma unroll
                    for (int p = 1; p < 10; ++p) m = fmaxf(m, row[8 * t + p]);
                    Ps[c][1 + t] = f2bf(m);
                }
            }
            if (lane < 2) Ps[c][lane * 101] = 0;
        }
    }
    __syncthreads();
    // conv k=3 p=1 + leaky -> xcs LDS
    for (int i = tid; i < 4 * T; i += 1024) {
        int o = i / T, t = i - o * T;
        float sum = b_sc[o];
        const float* wvp = w_sc + o * 192;
        for (int c = 0; c < 64; ++c) {
            float p0 = bf2f(Ps[c][t]), p1 = bf2f(Ps[c][t + 1]), p2 = bf2f(Ps[c][t + 2]);
            sum += wvp[c * 3] * p0 + wvp[c * 3 + 1] * p1 + wvp[c * 3 + 2] * p2;
        }
        xcs[o][t] = leaky(sum);
    }
    __syncthreads();
    // Xg phase: n = tid&255 gate column, tq = tid>>8 time-phase; pre-scaled
    {
        const int n = tid & 255, tq = tid >> 8;
        const int g = n >> 6;
        const float sc = (g == 2) ? (-2.0f * LOG2E) : (-LOG2E);
        const float4 w4 = *(const float4*)(w_ih + n * 4);
        const float bias = b_ih[n] + b_hh[n];
        const int bt = b >> 4, quad = (b >> 2) & 3, r = b & 3;
        const int hidx = n & 63;
        const int wv2 = hidx >> 4, l16 = hidx & 15;
        const size_t off0 = (((size_t)bt * 4 + wv2) * 64 + quad * 16 + l16) * 16 + g * 4 + r;
        for (int t = tq; t < T; t += 4) {
            float v = bias + w4.x * xcs[0][t] + w4.y * xcs[1][t]
                           + w4.z * xcs[2][t] + w4.w * xcs[3][t];
            Xg[(size_t)t * 16384 + off0] = sc * v;
        }
    }
}

// ---------------------------------------------------------------------------
// lstm (+fused head): grid (4 bt, 2 br), 256 thr, 1 wave/SIMD.
// Whh B-fragments pre-scaled by SCG[g]; activations via rcp(1+exp2(x)).
#define HPAD 72
__global__ __launch_bounds__(256) void lstm_kernel(
    const float* __restrict__ Xg0, const float* __restrict__ Xg1,
    const float* __restrict__ Whh0, const float* __restrict__ Whh1,
    const float* __restrict__ wl0, const float* __restrict__ bl0,
    const float* __restrict__ wl1, const float* __restrict__ bl1,
    float* __restrict__ brbuf, int* __restrict__ cnt,
    const float* __restrict__ w_rul, const float* __restrict__ b_rul,
    float* __restrict__ out) {
    const int bt = blockIdx.x;
    const int br = blockIdx.y;
    const int T = (br == 0) ? 300 : 100;
    const float* Xg = (br == 0) ? Xg0 : Xg1;
    const float* Whh = (br == 0) ? Whh0 : Whh1;
    const float* wl = (br == 0) ? wl0 : wl1;
    const float* bl = (br == 0) ? bl0 : bl1;
    const float C2L = -2.0f * LOG2E;

    __shared__ __align__(16) unsigned short h_lds[2][16][HPAD];
    __shared__ int lastf;

    const int tid = threadIdx.x;
    const int w = tid >> 6, lane = tid & 63, quad = lane >> 4, l16 = lane & 15;
    const int hidx = w * 16 + l16;

    bf16x8 Bf[4][2];
#pragma unroll
    for (int g = 0; g < 4; ++g) {
        const int n = g * 64 + hidx;
        const float scg = (g == 2) ? (-2.0f * LOG2E) : (-LOG2E);
#pragma unroll
        for (int kc = 0; kc < 2; ++kc) {
            const float* src = Whh + n * 64 + kc * 32 + quad * 8;
            bf16x8 v;
#pragma unroll
            for (int j = 0; j < 8; ++j) v[j] = (short)f2bf(src[j] * scg);
            Bf[g][kc] = v;
        }
    }

    for (int i = tid; i < 16 * HPAD; i += 256) (&h_lds[0][0][0])[i] = 0;

    const float* xp = Xg + ((size_t)bt * 4 + w) * 1024 + lane * 16;

    f32x4 xb0[4], xb1[4];
#pragma unroll
    for (int g = 0; g < 4; ++g) xb0[g] = *(const f32x4*)(xp + g * 4);
#pragma unroll
    for (int g = 0; g < 4; ++g) xb1[g] = *(const f32x4*)(xp + 16384 + g * 4);

    float c[4] = {0.f, 0.f, 0.f, 0.f};

    __syncthreads();

    auto step = [&](int t, f32x4* xb) {
        const unsigned short* hrow = &h_lds[t & 1][l16][0];
        bf16x8 A0 = *(const bf16x8*)(hrow + quad * 8);
        bf16x8 A1 = *(const bf16x8*)(hrow + 32 + quad * 8);
        f32x4 ac[4];
#pragma unroll
        for (int g = 0; g < 4; ++g) {
            ac[g] = __builtin_amdgcn_mfma_f32_16x16x32_bf16(A0, Bf[g][0], xb[g], 0, 0, 0);
            ac[g] = __builtin_amdgcn_mfma_f32_16x16x32_bf16(A1, Bf[g][1], ac[g], 0, 0, 0);
        }
        if (t + 2 < T) {
            const float* np = xp + (size_t)(t + 2) * 16384;
#pragma unroll
            for (int g = 0; g < 4; ++g) xb[g] = *(const f32x4*)(np + g * 4);
        }
        const int nb = (t + 1) & 1;
#pragma unroll
        for (int r = 0; r < 4; ++r) {
            float iv = rcp2(ac[0][r]);                 // sigm(i)
            float fv = rcp2(ac[1][r]);                 // sigm(f)
            float gv = 2.0f * rcp2(ac[2][r]) - 1.0f;   // tanh(g)
            float ov = rcp2(ac[3][r]);                 // sigm(o)
            float cs = fv * c[r] + iv * gv;
            c[r] = cs;
            float th = 2.0f * rcp2(cs * C2L) - 1.0f;   // tanh(c)
            h_lds[nb][quad * 4 + r][hidx] = f2bf(ov * th);
        }
        __syncthreads();
    };

    for (int t = 0; t < T; t += 2) {   // T even
        step(t, xb0);
        step(t + 1, xb1);
    }

    // final linear -> brbuf (device-scope atomic stores)
    if (tid < 16) {
        const unsigned short* hrow = &h_lds[0][tid][0];
        float s = bl[0];
        for (int j = 0; j < 64; ++j) s += bf2f(hrow[j]) * wl[j];
        atomicExch(&brbuf[br * 64 + bt * 16 + tid], s);
    }
    __syncthreads();
    __threadfence();
    if (tid == 0) {
        int old = atomicAdd(cnt, 1);
        lastf = (old == 7);
    }
    __syncthreads();
    if (lastf) {                       // last block computes the head
        __threadfence();
        if (tid < 64) {
            float v0 = atomicAdd(&brbuf[tid], 0.0f);        // atomic load
            float v1 = atomicAdd(&brbuf[64 + tid], 0.0f);
            float v = w_rul[0] * v0 + w_rul[1] * v1 + b_rul[0];
            out[tid] = sigm(v);
        }
    }
}

// ---------------------------------------------------------------------------
extern "C" void kernel_launch(void* const* d_in, const int* in_sizes, int n_in,
                              void* d_out, int out_size, void* d_ws, size_t ws_size,
                              hipStream_t stream) {
    const float* X     = (const float*)d_in[0];
    const float* w_dw  = (const float*)d_in[1];
    const float* b_dw  = (const float*)d_in[2];
    const float* w_pw  = (const float*)d_in[3];
    const float* b_pw  = (const float*)d_in[4];
    const float* w_c2  = (const float*)d_in[5];
    const float* b_c2  = (const float*)d_in[6];
    const float* w_sc0 = (const float*)d_in[7];
    const float* b_sc0 = (const float*)d_in[8];
    const float* w_ih0 = (const float*)d_in[9];
    const float* b_ih0 = (const float*)d_in[10];
    const float* w_hh0 = (const float*)d_in[11];
    const float* b_hh0 = (const float*)d_in[12];
    const float* w_l0  = (const float*)d_in[13];
    const float* b_l0  = (const float*)d_in[14];
    const float* w_sc1 = (const float*)d_in[15];
    const float* b_sc1 = (const float*)d_in[16];
    const float* w_ih1 = (const float*)d_in[17];
    const float* b_ih1 = (const float*)d_in[18];
    const float* w_hh1 = (const float*)d_in[19];
    const float* b_hh1 = (const float*)d_in[20];
    const float* w_l1  = (const float*)d_in[21];
    const float* b_l1  = (const float*)d_in[22];
    const float* w_rul = (const float*)d_in[23];
    const float* b_rul = (const float*)d_in[24];

    float* ws = (float*)d_ws;
    float* Xg0 = ws;                                           // 4,915,200 f
    float* Xg1 = ws + 4915200;                                 // 1,638,400 f
    unsigned short* S2b = (unsigned short*)(ws + 6553600);     // 64*32*812 sh
    float* S3    = ws + 7385088;                               // 3,284,992 f
    unsigned short* Wp1 = (unsigned short*)(ws + 10670080);    // 15,360 sh
    float* b_eff = ws + 10677760;                              // 32
    float* brbuf = ws + 10677792;                              // 128
    int*   cnt   = (int*)(ws + 10677920);                      // 1  (~42.7 MB)

    prep_kernel<<<16, 256, 0, stream>>>(w_dw, b_dw, w_pw, b_pw, Wp1, b_eff);
    conv1p_kernel<<<dim3(26, 64), 256, 0, stream>>>(X, Wp1, b_eff, S2b, cnt);
    conv2_kernel<<<dim3(13, 64), 256, 0, stream>>>(S2b, w_c2, b_c2, S3);
    branch_kernel<<<dim3(64, 2), 1024, 0, stream>>>(
        S3, w_sc0, b_sc0, w_ih0, b_ih0, b_hh0,
            w_sc1, b_sc1, w_ih1, b_ih1, b_hh1, Xg0, Xg1);
    lstm_kernel<<<dim3(4, 2), 256, 0, stream>>>(Xg0, Xg1, w_hh0, w_hh1,
                                                w_l0, b_l0, w_l1, b_l1,
                                                brbuf, cnt, w_rul, b_rul, (float*)d_out);
}